// Round 1
// baseline (417.184 us; speedup 1.0000x reference)
//
#include <hip/hip_runtime.h>

#define D 128
#define TD 384  // 3*D

// -------- K_prep: p[t] = sum_i v[i] * A[i*384 + t]  (ps|pd|pr concatenated) ----
__global__ void k_prep(const float* __restrict__ A, const float* __restrict__ v,
                       float* __restrict__ p) {
  __shared__ float vs[D];
  int t = threadIdx.x;
  if (t < D) vs[t] = v[t];
  __syncthreads();
  float acc = 0.f;
#pragma unroll 8
  for (int i = 0; i < D; ++i) acc += vs[i] * A[i * TD + t];
  p[t] = acc;
}

// -------- K_scores + histogram (fused): wave-per-node dot products; extra blocks
// do the dst histogram for the CSR build. ------------------------------------
__global__ void k_scores_hist(const float* __restrict__ h, const float* __restrict__ emb,
                              const float* __restrict__ p, const int* __restrict__ dst,
                              float* __restrict__ ss, float* __restrict__ sd,
                              float* __restrict__ sr, int* __restrict__ cnt,
                              int N, int R, int E, int nbScore) {
  int t = threadIdx.x;
  if ((int)blockIdx.x < nbScore) {
    __shared__ float pl[TD];
    pl[t] = p[t];
    if (t < TD - 256) pl[256 + t] = p[256 + t];
    __syncthreads();
    int w = blockIdx.x * 4 + (t >> 6);
    int l = t & 63;
    if (w < N) {
      float x0 = h[(size_t)w * D + l];
      float x1 = h[(size_t)w * D + 64 + l];
      float a = x0 * pl[l] + x1 * pl[64 + l];
      float b = x0 * pl[128 + l] + x1 * pl[192 + l];
#pragma unroll
      for (int o = 32; o; o >>= 1) { a += __shfl_xor(a, o); b += __shfl_xor(b, o); }
      if (l == 0) { ss[w] = a; sd[w] = b; }
    } else if (w < N + R) {
      int r = w - N;
      float x0 = emb[(size_t)r * D + l];
      float x1 = emb[(size_t)r * D + 64 + l];
      float c = x0 * pl[256 + l] + x1 * pl[320 + l];
#pragma unroll
      for (int o = 32; o; o >>= 1) c += __shfl_xor(c, o);
      if (l == 0) sr[r] = c;
    }
  } else {
    int i = (blockIdx.x - nbScore) * 256 + t;
    int stride = (gridDim.x - nbScore) * 256;
    for (; i < E; i += stride) atomicAdd(&cnt[dst[i]], 1);
  }
}

// -------- K_scan: single-block exclusive scan of cnt[0..N-1]; cnt[N]=E; cur=start
__global__ void k_scan(int* __restrict__ cnt, int* __restrict__ cur, int N) {
  __shared__ int wsum[16];
  __shared__ int carry_s;
  int t = threadIdx.x, lane = t & 63, wid = t >> 6;
  if (t == 0) carry_s = 0;
  __syncthreads();
  for (int base = 0; base < N; base += 1024) {
    int carry = carry_s;
    int i = base + t;
    int v = (i < N) ? cnt[i] : 0;
    int x = v;
#pragma unroll
    for (int o = 1; o < 64; o <<= 1) {
      int y = __shfl_up(x, o);
      if (lane >= o) x += y;
    }
    if (lane == 63) wsum[wid] = x;
    __syncthreads();
    if (t < 16) {
      int y = wsum[t];
#pragma unroll
      for (int o = 1; o < 16; o <<= 1) {
        int z = __shfl_up(y, o);
        if (t >= o) y += z;
      }
      wsum[t] = y;
    }
    __syncthreads();
    int woff = (wid == 0) ? 0 : wsum[wid - 1];
    int excl = carry + woff + x - v;
    if (i < N) { cnt[i] = excl; cur[i] = excl; }
    if (t == 0) carry_s = carry + wsum[15];
    __syncthreads();
  }
  if (t == 0) cnt[N] = carry_s;
}

// -------- K_edge: per-edge logit + scatter into dst-sorted order --------------
__global__ void k_edge(const int* __restrict__ src, const int* __restrict__ dst,
                       const int* __restrict__ et, const float* __restrict__ ss,
                       const float* __restrict__ sd, const float* __restrict__ sr,
                       int* __restrict__ cur, float* __restrict__ esort,
                       int* __restrict__ ssort, int E) {
  int i = blockIdx.x * blockDim.x + threadIdx.x;
  if (i >= E) return;
  int s = src[i], d = dst[i], r = et[i];
  float e = ss[s] + sd[d] + sr[r];
  e = (e > 0.f) ? e : 0.01f * e;
  int pos = atomicAdd(&cur[d], 1);
  esort[pos] = e;
  ssort[pos] = s;
}

// -------- K_agg: one block per dst node. max -> exp/denom -> weighted gather --
__global__ __launch_bounds__(128) void k_agg(const float* __restrict__ h,
                                             const int* __restrict__ off,
                                             const float* __restrict__ esort,
                                             const int* __restrict__ ssort,
                                             float* __restrict__ out, int N) {
  int n = blockIdx.x;
  int t = threadIdx.x;
  int start = off[n], end = off[n + 1];
  int deg = end - start;
  if (deg == 0) {                       // block-uniform: DGL keeps h unchanged
    out[(size_t)n * D + t] = h[(size_t)n * D + t];
    return;
  }
  int lane = t & 63, wid = t >> 6;
  __shared__ float mred[2];
  __shared__ float sred[2];
  __shared__ float wch[128];
  __shared__ int sch[128];

  // pass A: segment max
  float m = -3.4e38f;
  for (int i = t; i < deg; i += 128) m = fmaxf(m, esort[start + i]);
#pragma unroll
  for (int o = 32; o; o >>= 1) m = fmaxf(m, __shfl_xor(m, o));
  if (lane == 0) mred[wid] = m;
  __syncthreads();
  m = fmaxf(mred[0], mred[1]);

  // pass B+C: chunked exp into LDS, feature accumulation, denom on the side
  float acc = 0.f;
  float wpriv = 0.f;
  for (int cs = 0; cs < deg; cs += 128) {
    int cn = min(128, deg - cs);
    __syncthreads();
    if (t < cn) {
      float w = __expf(esort[start + cs + t] - m);
      wpriv += w;
      wch[t] = w;
      sch[t] = ssort[start + cs + t];
    }
    __syncthreads();
#pragma unroll 4
    for (int i = 0; i < cn; ++i) acc += wch[i] * h[(size_t)sch[i] * D + t];
  }
#pragma unroll
  for (int o = 32; o; o >>= 1) wpriv += __shfl_xor(wpriv, o);
  if (lane == 0) sred[wid] = wpriv;
  __syncthreads();
  float denom = sred[0] + sred[1];
  out[(size_t)n * D + t] = acc / denom;
}

// -------- K_final: out += h @ loop_weight (W cached in LDS, 2 nodes/iter) -----
__global__ __launch_bounds__(256) void k_final(const float* __restrict__ h,
                                               const float* __restrict__ lw,
                                               float* __restrict__ out, int N) {
  __shared__ float Wl[D * D];           // 64 KB
  __shared__ float hl[2][D];
  int t = threadIdx.x;
  for (int i = t; i < D * D / 4; i += 256)
    ((float4*)Wl)[i] = ((const float4*)lw)[i];
  int half = t >> 7;
  int j = t & 127;
  int npairs = (N + 1) / 2;
  for (int pr = blockIdx.x; pr < npairs; pr += gridDim.x) {
    int n = pr * 2 + half;
    __syncthreads();                    // protect hl reuse (and Wl on iter 0)
    if (n < N) hl[half][j] = h[(size_t)n * D + j];
    __syncthreads();
    if (n < N) {
      float acc = 0.f;
#pragma unroll 8
      for (int k = 0; k < D; ++k) acc += hl[half][k] * Wl[k * D + j];
      out[(size_t)n * D + j] += acc;
    }
  }
}

extern "C" void kernel_launch(void* const* d_in, const int* in_sizes, int n_in,
                              void* d_out, int out_size, void* d_ws, size_t ws_size,
                              hipStream_t stream) {
  const float* h   = (const float*)d_in[0];
  const float* emb = (const float*)d_in[1];
  const float* lw  = (const float*)d_in[2];
  const float* afw = (const float*)d_in[3];
  const float* af2 = (const float*)d_in[4];
  const int* src = (const int*)d_in[5];
  const int* dst = (const int*)d_in[6];
  const int* et  = (const int*)d_in[7];
  int N = in_sizes[0] / D;
  int R = in_sizes[1] / D;
  int E = in_sizes[5];
  float* out = (float*)d_out;

  char* ws = (char*)d_ws;
  size_t o = 0;
  auto alloc = [&](size_t bytes) -> void* {
    void* pp = ws + o;
    o = (o + bytes + 255) & ~(size_t)255;
    return pp;
  };
  float* p     = (float*)alloc((size_t)TD * 4);
  float* ss    = (float*)alloc((size_t)N * 4);
  float* sd    = (float*)alloc((size_t)N * 4);
  float* srel  = (float*)alloc((size_t)R * 4);
  int*   cnt   = (int*)  alloc((size_t)(N + 1) * 4);
  int*   cur   = (int*)  alloc((size_t)N * 4);
  float* esort = (float*)alloc((size_t)E * 4);
  int*   ssort = (int*)  alloc((size_t)E * 4);

  hipMemsetAsync(cnt, 0, (size_t)(N + 1) * 4, stream);
  k_prep<<<1, TD, 0, stream>>>(afw, af2, p);
  int nbScore = (N + R + 3) / 4;
  int nbHist = 2048;
  k_scores_hist<<<nbScore + nbHist, 256, 0, stream>>>(h, emb, p, dst, ss, sd, srel,
                                                      cnt, N, R, E, nbScore);
  k_scan<<<1, 1024, 0, stream>>>(cnt, cur, N);
  k_edge<<<(E + 255) / 256, 256, 0, stream>>>(src, dst, et, ss, sd, srel, cur,
                                              esort, ssort, E);
  k_agg<<<N, 128, 0, stream>>>(h, cnt, esort, ssort, out, N);
  k_final<<<1024, 256, 0, stream>>>(h, lw, out, N);
}

// Round 3
// 334.515 us; speedup vs baseline: 1.2471x; 1.2471x over previous
//
#include <hip/hip_runtime.h>

#define D 128
#define TD 384  // 3*D

// -------- K_prep: p[t] = sum_i v[i] * A[i*384 + t]  (ps|pd|pr concatenated) ----
__global__ void k_prep(const float* __restrict__ A, const float* __restrict__ v,
                       float* __restrict__ p) {
  __shared__ float vs[D];
  int t = threadIdx.x;
  if (t < D) vs[t] = v[t];
  __syncthreads();
  float acc = 0.f;
#pragma unroll 8
  for (int i = 0; i < D; ++i) acc += vs[i] * A[i * TD + t];
  p[t] = acc;
}

// -------- K_scores + histogram (fused): wave-per-node dot products; extra blocks
// do the dst histogram for the CSR build. ------------------------------------
__global__ void k_scores_hist(const float* __restrict__ h, const float* __restrict__ emb,
                              const float* __restrict__ p, const int* __restrict__ dst,
                              float* __restrict__ ss, float* __restrict__ sd,
                              float* __restrict__ sr, int* __restrict__ cnt,
                              int N, int R, int E, int nbScore) {
  int t = threadIdx.x;
  if ((int)blockIdx.x < nbScore) {
    __shared__ float pl[TD];
    pl[t] = p[t];
    if (t < TD - 256) pl[256 + t] = p[256 + t];
    __syncthreads();
    int w = blockIdx.x * 4 + (t >> 6);
    int l = t & 63;
    if (w < N) {
      float x0 = h[(size_t)w * D + l];
      float x1 = h[(size_t)w * D + 64 + l];
      float a = x0 * pl[l] + x1 * pl[64 + l];
      float b = x0 * pl[128 + l] + x1 * pl[192 + l];
#pragma unroll
      for (int o = 32; o; o >>= 1) { a += __shfl_xor(a, o); b += __shfl_xor(b, o); }
      if (l == 0) { ss[w] = a; sd[w] = b; }
    } else if (w < N + R) {
      int r = w - N;
      float x0 = emb[(size_t)r * D + l];
      float x1 = emb[(size_t)r * D + 64 + l];
      float c = x0 * pl[256 + l] + x1 * pl[320 + l];
#pragma unroll
      for (int o = 32; o; o >>= 1) c += __shfl_xor(c, o);
      if (l == 0) sr[r] = c;
    }
  } else {
    int i = (blockIdx.x - nbScore) * 256 + t;
    int stride = (gridDim.x - nbScore) * 256;
    for (; i < E; i += stride) atomicAdd(&cnt[dst[i]], 1);
  }
}

// -------- 3-phase exclusive scan of cnt[0..N-1] (replaces single-block scan) --
__global__ void k_scan1(int* __restrict__ cnt, int* __restrict__ bsum, int N) {
  __shared__ int wsum[16];
  int t = threadIdx.x, lane = t & 63, wid = t >> 6;
  int i = blockIdx.x * 1024 + t;
  int v = (i < N) ? cnt[i] : 0;
  int x = v;
#pragma unroll
  for (int o = 1; o < 64; o <<= 1) {
    int y = __shfl_up(x, o);
    if (lane >= o) x += y;
  }
  if (lane == 63) wsum[wid] = x;
  __syncthreads();
  if (t < 16) {
    int y = wsum[t];
#pragma unroll
    for (int o = 1; o < 16; o <<= 1) {
      int z = __shfl_up(y, o);
      if (t >= o) y += z;
    }
    wsum[t] = y;
  }
  __syncthreads();
  int woff = wid ? wsum[wid - 1] : 0;
  if (i < N) cnt[i] = woff + x - v;     // block-local exclusive scan
  if (t == 0) bsum[blockIdx.x] = wsum[15];
}

__global__ void k_scan2(int* __restrict__ bsum, int nsb) {
  int l = threadIdx.x;
  int v = (l < nsb) ? bsum[l] : 0;
  int x = v;
#pragma unroll
  for (int o = 1; o < 64; o <<= 1) {
    int y = __shfl_up(x, o);
    if (l >= o) x += y;
  }
  if (l < nsb) bsum[l] = x - v;          // exclusive block offsets, in place
}

__global__ void k_scan3(const int* __restrict__ bsum, int* __restrict__ cnt,
                        int* __restrict__ cur, int N, int E) {
  int i = blockIdx.x * 1024 + threadIdx.x;
  if (i < N) {
    int v = cnt[i] + bsum[blockIdx.x];
    cnt[i] = v;
    cur[i] = v;
  }
  if (i == 0) cnt[N] = E;
}

// -------- K_edge: per-edge logit + scatter into dst-sorted order --------------
__global__ void k_edge(const int* __restrict__ src, const int* __restrict__ dst,
                       const int* __restrict__ et, const float* __restrict__ ss,
                       const float* __restrict__ sd, const float* __restrict__ sr,
                       int* __restrict__ cur, float* __restrict__ esort,
                       int* __restrict__ ssort, int E) {
  int i = blockIdx.x * blockDim.x + threadIdx.x;
  if (i >= E) return;
  int s = src[i], d = dst[i], r = et[i];
  float e = ss[s] + sd[d] + sr[r];
  e = (e > 0.f) ? e : 0.01f * e;
  int pos = atomicAdd(&cur[d], 1);
  esort[pos] = e;
  ssort[pos] = s;
}

// -------- K_agg: one block per dst node. max -> exp/denom -> weighted gather --
__global__ __launch_bounds__(128) void k_agg(const float* __restrict__ h,
                                             const int* __restrict__ off,
                                             const float* __restrict__ esort,
                                             const int* __restrict__ ssort,
                                             float* __restrict__ out, int N) {
  int n = blockIdx.x;
  int t = threadIdx.x;
  int start = off[n], end = off[n + 1];
  int deg = end - start;
  if (deg == 0) {                       // block-uniform: DGL keeps h unchanged
    out[(size_t)n * D + t] = h[(size_t)n * D + t];
    return;
  }
  int lane = t & 63, wid = t >> 6;
  __shared__ float mred[2];
  __shared__ float sred[2];
  __shared__ float wch[128];
  __shared__ int sch[128];

  // pass A: segment max
  float m = -3.4e38f;
  for (int i = t; i < deg; i += 128) m = fmaxf(m, esort[start + i]);
#pragma unroll
  for (int o = 32; o; o >>= 1) m = fmaxf(m, __shfl_xor(m, o));
  if (lane == 0) mred[wid] = m;
  __syncthreads();
  m = fmaxf(mred[0], mred[1]);

  // pass B+C: chunked exp into LDS, feature accumulation, denom on the side
  float acc = 0.f;
  float wpriv = 0.f;
  for (int cs = 0; cs < deg; cs += 128) {
    int cn = min(128, deg - cs);
    __syncthreads();
    if (t < cn) {
      float w = __expf(esort[start + cs + t] - m);
      wpriv += w;
      wch[t] = w;
      sch[t] = ssort[start + cs + t];
    }
    __syncthreads();
#pragma unroll 4
    for (int i = 0; i < cn; ++i) acc += wch[i] * h[(size_t)sch[i] * D + t];
  }
#pragma unroll
  for (int o = 32; o; o >>= 1) wpriv += __shfl_xor(wpriv, o);
  if (lane == 0) sred[wid] = wpriv;
  __syncthreads();
  float denom = sred[0] + sred[1];
  out[(size_t)n * D + t] = acc / denom;
}

// -------- K_final: out += h @ loop_weight. W column in registers (one column
// per thread); h row read via wave-UNIFORM addresses (block processes one node
// per iter, addr derived from blockIdx/loop only) so the compiler scalarizes
// them to s_load through the constant cache -> zero vector-mem / LDS per FMA.
__global__ __launch_bounds__(128) void k_final(const float* __restrict__ h,
                                               const float* __restrict__ lw,
                                               float* __restrict__ out, int N) {
  int j = threadIdx.x;                  // output column, 0..127
  float w[D];                           // W[:, j] in registers
#pragma unroll
  for (int k = 0; k < D; ++k) w[k] = lw[(size_t)k * D + j];
  for (int n = blockIdx.x; n < N; n += gridDim.x) {
    const float4* __restrict__ hr4 =
        reinterpret_cast<const float4*>(h + (size_t)n * D);  // uniform address
    float acc = 0.f;
#pragma unroll
    for (int q = 0; q < D / 4; ++q) {
      float4 hv = hr4[q];
      acc = fmaf(hv.x, w[4 * q + 0], acc);
      acc = fmaf(hv.y, w[4 * q + 1], acc);
      acc = fmaf(hv.z, w[4 * q + 2], acc);
      acc = fmaf(hv.w, w[4 * q + 3], acc);
    }
    out[(size_t)n * D + j] += acc;
  }
}

extern "C" void kernel_launch(void* const* d_in, const int* in_sizes, int n_in,
                              void* d_out, int out_size, void* d_ws, size_t ws_size,
                              hipStream_t stream) {
  const float* h   = (const float*)d_in[0];
  const float* emb = (const float*)d_in[1];
  const float* lw  = (const float*)d_in[2];
  const float* afw = (const float*)d_in[3];
  const float* af2 = (const float*)d_in[4];
  const int* src = (const int*)d_in[5];
  const int* dst = (const int*)d_in[6];
  const int* et  = (const int*)d_in[7];
  int N = in_sizes[0] / D;
  int R = in_sizes[1] / D;
  int E = in_sizes[5];
  float* out = (float*)d_out;

  char* ws = (char*)d_ws;
  size_t o = 0;
  auto alloc = [&](size_t bytes) -> void* {
    void* pp = ws + o;
    o = (o + bytes + 255) & ~(size_t)255;
    return pp;
  };
  float* p     = (float*)alloc((size_t)TD * 4);
  float* ss    = (float*)alloc((size_t)N * 4);
  float* sd    = (float*)alloc((size_t)N * 4);
  float* srel  = (float*)alloc((size_t)R * 4);
  int*   cnt   = (int*)  alloc((size_t)(N + 1) * 4);
  int*   cur   = (int*)  alloc((size_t)N * 4);
  int*   bsum  = (int*)  alloc((size_t)64 * 4);
  float* esort = (float*)alloc((size_t)E * 4);
  int*   ssort = (int*)  alloc((size_t)E * 4);

  int nsb = (N + 1023) / 1024;          // 49 for N=50000 (<= 64 for scan2 wave)

  hipMemsetAsync(cnt, 0, (size_t)(N + 1) * 4, stream);
  k_prep<<<1, TD, 0, stream>>>(afw, af2, p);
  int nbScore = (N + R + 3) / 4;
  int nbHist = 2048;
  k_scores_hist<<<nbScore + nbHist, 256, 0, stream>>>(h, emb, p, dst, ss, sd, srel,
                                                      cnt, N, R, E, nbScore);
  k_scan1<<<nsb, 1024, 0, stream>>>(cnt, bsum, N);
  k_scan2<<<1, 64, 0, stream>>>(bsum, nsb);
  k_scan3<<<nsb, 1024, 0, stream>>>(bsum, cnt, cur, N, E);
  k_edge<<<(E + 255) / 256, 256, 0, stream>>>(src, dst, et, ss, sd, srel, cur,
                                              esort, ssort, E);
  k_agg<<<N, 128, 0, stream>>>(h, cnt, esort, ssort, out, N);
  k_final<<<2048, 128, 0, stream>>>(h, lw, out, N);
}